// Round 1
// baseline (292.704 us; speedup 1.0000x reference)
//
#include <hip/hip_runtime.h>

// GraphConsis fused encoder + dot.
// B=4096, H=50, A=32, L=82, D=64, tables 100000x64 f32.
//
// Key algorithmic reductions vs reference:
//  - _q (agg_W/agg_b) is dead code -> skipped; target_tab gather skipped.
//  - rate_feat only enters via dot(r2e[r], relation_att[64:]) -> 7 scalars.
//  - online softmax: single pass over the 82 gathered embeddings.
//
// Layout: block = 256 threads = 4 waves. Waves 0,1 = user side rows (2b, 2b+1);
// waves 2,3 = item side rows (2b, 2b+1). One wave per row, lane = dim.
// Final eu.ev dot done in-block through LDS.

#define NB 4096
#define NH 50
#define NA 32
#define NL 82
#define ND 64

__global__ __launch_bounds__(256, 4) void graphconsis_kernel(
    const float* __restrict__ u2e, const float* __restrict__ v2e,
    const float* __restrict__ r2e, const float* __restrict__ ra,
    const float* __restrict__ lin1_W, const float* __restrict__ lin1_b,
    const int* __restrict__ nodes_u, const int* __restrict__ nodes_v,
    const int* __restrict__ hist_u, const int* __restrict__ hist_ur,
    const int* __restrict__ adj_u,
    const int* __restrict__ hist_v, const int* __restrict__ hist_vr,
    const int* __restrict__ adj_v,
    float* __restrict__ out)
{
    // LDS: transposed lin1_W (padded, conflict-free), 7 rate logits, e-vectors.
    __shared__ float Wt[128][65];   // Wt[k][j] = lin1_W[j*128 + k]
    __shared__ float rlog[7];
    __shared__ float ed[4][64];

    // Cooperative load of lin1_W, transposed into LDS (float4 global reads).
    {
        const float4* w4 = (const float4*)lin1_W;
        for (int i = threadIdx.x; i < 2048; i += 256) {
            float4 v = w4[i];
            int fi = i * 4;
            int j = fi >> 7;       // row of lin1_W (output dim)
            int k = fi & 127;      // col (input dim)
            Wt[k + 0][j] = v.x;
            Wt[k + 1][j] = v.y;
            Wt[k + 2][j] = v.z;
            Wt[k + 3][j] = v.w;
        }
    }
    // 7 rate logits: dot(r2e[r], ra[64:128])
    if (threadIdx.x < 7) {
        float sum = 0.f;
        #pragma unroll
        for (int d = 0; d < 64; ++d)
            sum += r2e[threadIdx.x * 64 + d] * ra[64 + d];
        rlog[threadIdx.x] = sum;
    }
    __syncthreads();

    const int wid  = threadIdx.x >> 6;
    const int lane = threadIdx.x & 63;
    const int b    = blockIdx.x * 2 + (wid & 1);
    const int side = wid >> 1;   // 0 = user, 1 = item

    const float* nodeTab  = side ? v2e : u2e;
    const float* histTab  = side ? u2e : v2e;
    const float* neighTab = side ? v2e : u2e;
    const int* nodes = side ? nodes_v : nodes_u;
    const int* hn    = side ? hist_v  : hist_u;
    const int* hr    = side ? hist_vr : hist_ur;
    const int* adj   = side ? adj_v   : adj_u;

    const float ra_lo = ra[lane];

    // self node feature
    const int nidx = nodes[b];
    const float nf = nodeTab[nidx * 64 + lane];

    // preload 82 gather indices into 2 regs/lane; rate-logit adds for l<50
    int idx0 = (lane < NH) ? hn[b * NH + lane] : adj[b * NA + (lane - NH)];
    int idx1 = (lane < NL - 64) ? adj[b * NA + (14 + lane)] : 0;
    float rl0 = (lane < NH) ? rlog[hr[b * NH + lane]] : 0.f;
    const float rlog6 = rlog[6];

    // online softmax over 82 entries, single pass
    float m = -3.0e38f, s = 0.f, acc = 0.f;
    #pragma unroll 4
    for (int l = 0; l < NL; ++l) {
        int idx = (l < 64) ? __shfl(idx0, l) : __shfl(idx1, l - 64);
        const float* base = (l < NH) ? histTab : neighTab;
        float e = base[idx * 64 + lane];
        float part = e * ra_lo;
        #pragma unroll
        for (int off = 32; off >= 1; off >>= 1)
            part += __shfl_xor(part, off);
        float logit = part + ((l < NH) ? __shfl(rl0, l) : rlog6);
        float nm = fmaxf(m, logit);
        float sc = __expf(m - nm);
        float p  = __expf(logit - nm);
        s   = s * sc + p;
        acc = acc * sc + p * e;
        m = nm;
    }
    const float neigh = acc / s;

    // out_j = relu(lin1_b[j] + sum_k lin1_W[j][k] * comb[k]), comb=[nf; neigh]
    float o = lin1_b[lane];
    #pragma unroll 8
    for (int k = 0; k < 64; ++k)
        o = fmaf(Wt[k][lane], __shfl(nf, k), o);
    #pragma unroll 8
    for (int k = 0; k < 64; ++k)
        o = fmaf(Wt[64 + k][lane], __shfl(neigh, k), o);
    const float evec = fmaxf(o, 0.f);

    ed[wid][lane] = evec;
    __syncthreads();

    if (wid < 2) {
        float prod = ed[wid][lane] * ed[wid + 2][lane];
        #pragma unroll
        for (int off = 32; off >= 1; off >>= 1)
            prod += __shfl_xor(prod, off);
        if (lane == 0) out[blockIdx.x * 2 + wid] = prod;
    }
}

extern "C" void kernel_launch(void* const* d_in, const int* in_sizes, int n_in,
                              void* d_out, int out_size, void* d_ws, size_t ws_size,
                              hipStream_t stream)
{
    const float* u2e     = (const float*)d_in[0];
    const float* v2e     = (const float*)d_in[1];
    const float* r2e     = (const float*)d_in[2];
    const float* ra      = (const float*)d_in[3];
    // d_in[4] agg_W, d_in[5] agg_b: dead code in the reference (unused _q)
    const float* lin1_W  = (const float*)d_in[6];
    const float* lin1_b  = (const float*)d_in[7];
    const int* nodes_u   = (const int*)d_in[8];
    const int* nodes_v   = (const int*)d_in[9];
    const int* hist_u    = (const int*)d_in[10];
    const int* hist_ur   = (const int*)d_in[11];
    const int* adj_u     = (const int*)d_in[12];
    const int* hist_v    = (const int*)d_in[13];
    const int* hist_vr   = (const int*)d_in[14];
    const int* adj_v     = (const int*)d_in[15];
    float* out = (float*)d_out;

    dim3 grid(NB / 2), block(256);
    hipLaunchKernelGGL(graphconsis_kernel, grid, block, 0, stream,
                       u2e, v2e, r2e, ra, lin1_W, lin1_b,
                       nodes_u, nodes_v, hist_u, hist_ur, adj_u,
                       hist_v, hist_vr, adj_v, out);
}

// Round 2
// 63.482 us; speedup vs baseline: 4.6108x; 4.6108x over previous
//
#include <hip/hip_runtime.h>

// GraphConsis fused encoder + dot — round 1.
// B=4096, H=50, A=32, L=82, D=64, tables 100000x64 f32.
//
// vs round 0:
//  - no 33KB Wt LDS tile -> LDS ~3KB -> 8 blocks/CU (was 4): 2x occupancy
//  - index loads made wave-uniform (readfirstlane) -> SMEM s_load, no DS bcast
//  - rate logit folded into butterfly pre-reduce (lane==l trick), no DS bcast
//  - softmax with fixed shift 0 (no max chain); shift-invariant, range safe
//  - lin1 applied per-wave: W rows streamed per-lane (L1-resident), comb via
//    uniform-address ds_read_b128 broadcast from a 512B per-wave LDS slice
//  - rlog[7] precomputed by a tiny setup kernel into d_ws

#define NB 4096
#define NH 50
#define NA 32
#define ND 64

__global__ void rlog_setup(const float* __restrict__ r2e,
                           const float* __restrict__ ra,
                           float* __restrict__ ws_rlog)
{
    const int lane = threadIdx.x;            // 64 threads
    const float ra_hi = ra[64 + lane];
    #pragma unroll
    for (int r = 0; r < 7; ++r) {
        float part = r2e[r * 64 + lane] * ra_hi;
        #pragma unroll
        for (int off = 32; off >= 1; off >>= 1)
            part += __shfl_xor(part, off);
        if (lane == 0) ws_rlog[r] = part;
    }
}

__global__ __launch_bounds__(256, 8) void graphconsis_main(
    const float* __restrict__ u2e, const float* __restrict__ v2e,
    const float* __restrict__ ra,
    const float* __restrict__ lin1_W, const float* __restrict__ lin1_b,
    const int* __restrict__ nodes_u, const int* __restrict__ nodes_v,
    const int* __restrict__ hist_u, const int* __restrict__ hist_ur,
    const int* __restrict__ adj_u,
    const int* __restrict__ hist_v, const int* __restrict__ hist_vr,
    const int* __restrict__ adj_v,
    const float* __restrict__ ws_rlog,
    float* __restrict__ out)
{
    __shared__ float lds_comb[4][128];   // per-wave comb slice (512B each)
    __shared__ float ed[4][64];          // evec exchange for the final dot

    const int wid  = threadIdx.x >> 6;
    const int lane = threadIdx.x & 63;
    const int side = wid >> 1;                       // 0 = user, 1 = item
    const int b    = __builtin_amdgcn_readfirstlane(blockIdx.x * 2 + (wid & 1));

    const float* nodeTab  = side ? v2e : u2e;
    const float* histTab  = side ? u2e : v2e;
    const float* neighTab = side ? v2e : u2e;
    const int* nodes = side ? nodes_v : nodes_u;
    const int* hn    = side ? hist_v  : hist_u;
    const int* hr    = side ? hist_vr : hist_ur;
    const int* adj   = side ? adj_v   : adj_u;

    const float ra_lo = ra[lane];
    const float rlog6 = ws_rlog[6];

    const float nf = nodeTab[nodes[b] * ND + lane];

    // per-lane rate logit for history entry `lane` (used via lane==l trick)
    float rl0 = 0.f;
    if (lane < NH) rl0 = ws_rlog[hr[b * NH + lane]];

    float ssum = 0.f, acc = 0.f;

    // history entries 0..49 (uniform s_load indices, coalesced 256B gathers)
    #pragma unroll 10
    for (int l = 0; l < NH; ++l) {
        const int idx = hn[b * NH + l];              // wave-uniform -> SMEM
        const float e = histTab[idx * ND + lane];
        float part = fmaf(e, ra_lo, (lane == l) ? rl0 : 0.f);
        #pragma unroll
        for (int off = 32; off >= 1; off >>= 1)
            part += __shfl_xor(part, off);
        const float p = __expf(part);
        ssum += p;
        acc = fmaf(p, e, acc);
    }
    // neighbor entries 0..31 (all have rate 6 -> scalar rlog6 add)
    #pragma unroll 8
    for (int l = 0; l < NA; ++l) {
        const int idx = adj[b * NA + l];             // wave-uniform -> SMEM
        const float e = neighTab[idx * ND + lane];
        float part = e * ra_lo;
        #pragma unroll
        for (int off = 32; off >= 1; off >>= 1)
            part += __shfl_xor(part, off);
        const float p = __expf(part + rlog6);
        ssum += p;
        acc = fmaf(p, e, acc);
    }
    const float neigh = acc / ssum;

    // comb -> own LDS slice (wave-local, no barrier needed)
    lds_comb[wid][lane]      = nf;
    lds_comb[wid][64 + lane] = neigh;

    // out_j = relu(b_j + sum_k W[j][k] * comb[k]); lane = j
    // W row j streamed per-lane (L1-resident 32KB); comb broadcast via
    // uniform-address ds_read_b128.
    float o = lin1_b[lane];
    const float4* W4 = (const float4*)(lin1_W + lane * 128);
    const float4* C4 = (const float4*)lds_comb[wid];
    #pragma unroll 8
    for (int kk = 0; kk < 32; ++kk) {
        const float4 w = W4[kk];
        const float4 c = C4[kk];
        o = fmaf(w.x, c.x, o);
        o = fmaf(w.y, c.y, o);
        o = fmaf(w.z, c.z, o);
        o = fmaf(w.w, c.w, o);
    }
    const float evec = fmaxf(o, 0.f);

    ed[wid][lane] = evec;
    __syncthreads();

    if (wid < 2) {
        float prod = ed[wid][lane] * ed[wid + 2][lane];
        #pragma unroll
        for (int off = 32; off >= 1; off >>= 1)
            prod += __shfl_xor(prod, off);
        if (lane == 0) out[blockIdx.x * 2 + wid] = prod;
    }
}

extern "C" void kernel_launch(void* const* d_in, const int* in_sizes, int n_in,
                              void* d_out, int out_size, void* d_ws, size_t ws_size,
                              hipStream_t stream)
{
    const float* u2e     = (const float*)d_in[0];
    const float* v2e     = (const float*)d_in[1];
    const float* r2e     = (const float*)d_in[2];
    const float* ra      = (const float*)d_in[3];
    // d_in[4] agg_W, d_in[5] agg_b: dead code in the reference
    const float* lin1_W  = (const float*)d_in[6];
    const float* lin1_b  = (const float*)d_in[7];
    const int* nodes_u   = (const int*)d_in[8];
    const int* nodes_v   = (const int*)d_in[9];
    const int* hist_u    = (const int*)d_in[10];
    const int* hist_ur   = (const int*)d_in[11];
    const int* adj_u     = (const int*)d_in[12];
    const int* hist_v    = (const int*)d_in[13];
    const int* hist_vr   = (const int*)d_in[14];
    const int* adj_v     = (const int*)d_in[15];
    float* out = (float*)d_out;
    float* ws_rlog = (float*)d_ws;

    hipLaunchKernelGGL(rlog_setup, dim3(1), dim3(64), 0, stream, r2e, ra, ws_rlog);
    hipLaunchKernelGGL(graphconsis_main, dim3(NB / 2), dim3(256), 0, stream,
                       u2e, v2e, ra, lin1_W, lin1_b,
                       nodes_u, nodes_v, hist_u, hist_ur, adj_u,
                       hist_v, hist_vr, adj_v, ws_rlog, out);
}

// Round 3
// 59.135 us; speedup vs baseline: 4.9498x; 1.0735x over previous
//
#include <hip/hip_runtime.h>

// GraphConsis fused encoder + dot — round 2.
// B=4096, H=50, A=32, L=82, D=64, tables 100000x64 f32.
//
// vs round 1 (63.5us, latency-bound on per-entry 6-step 64-lane butterflies):
//  - wave reshaped as 4 entry-groups x 16 lanes; lane (g,j) holds dims 4j..4j+3
//    of entry 4k+g as float4 -> one dwordx4 gather serves 4 entries, and the
//    logit reduce is a 4-step xor within 16 lanes handling 4 entries at once:
//    cross-lane ops per entry 6 -> 1, VMEM instrs per entry 1 -> 0.25.
//  - rate logit folded pre-reduce via (j==k) lane trick; adj rate is scalar.
//  - groups combined once at the end (xor 16,32 on float4 acc + ssum).

#define NB 4096
#define NH 50
#define NA 32
#define ND 64

__global__ void rlog_setup(const float* __restrict__ r2e,
                           const float* __restrict__ ra,
                           float* __restrict__ ws_rlog)
{
    const int lane = threadIdx.x;            // 64 threads
    const float ra_hi = ra[64 + lane];
    #pragma unroll
    for (int r = 0; r < 7; ++r) {
        float part = r2e[r * 64 + lane] * ra_hi;
        #pragma unroll
        for (int off = 32; off >= 1; off >>= 1)
            part += __shfl_xor(part, off);
        if (lane == 0) ws_rlog[r] = part;
    }
}

__global__ __launch_bounds__(256, 8) void graphconsis_main(
    const float* __restrict__ u2e, const float* __restrict__ v2e,
    const float* __restrict__ ra,
    const float* __restrict__ lin1_W, const float* __restrict__ lin1_b,
    const int* __restrict__ nodes_u, const int* __restrict__ nodes_v,
    const int* __restrict__ hist_u, const int* __restrict__ hist_ur,
    const int* __restrict__ adj_u,
    const int* __restrict__ hist_v, const int* __restrict__ hist_vr,
    const int* __restrict__ adj_v,
    const float* __restrict__ ws_rlog,
    float* __restrict__ out)
{
    __shared__ float lds_comb[4][128];   // per-wave comb slice
    __shared__ float ed[4][64];          // evec exchange for the final dot

    const int wid  = threadIdx.x >> 6;
    const int lane = threadIdx.x & 63;
    const int g    = lane >> 4;          // entry subgroup 0..3
    const int j    = lane & 15;          // dim-quad index
    const int side = wid >> 1;           // 0 = user, 1 = item
    const int b    = __builtin_amdgcn_readfirstlane(blockIdx.x * 2 + (wid & 1));

    const float* nodeTab  = side ? v2e : u2e;
    const float* histTab  = side ? u2e : v2e;
    const float* neighTab = side ? v2e : u2e;
    const int* nodes = side ? nodes_v : nodes_u;
    const int* hn    = side ? hist_v  : hist_u;
    const int* hr    = side ? hist_vr : hist_ur;
    const int* adj   = side ? adj_v   : adj_u;

    const float4 ra4  = *(const float4*)(ra + 4 * j);
    const float rlog6 = ws_rlog[6];

    // preload history indices: lane (g,j) needs entry 4k+g at iteration k
    int hidx[13];
    #pragma unroll
    for (int k = 0; k < 13; ++k) {
        int l = 4 * k + g; if (l > NH - 1) l = NH - 1;
        hidx[k] = hn[b * NH + l];
    }
    // per-lane rate logit for history entry 4j+g (consumed at iter k==j)
    float rl0 = 0.f;
    { int l = 4 * j + g; if (l < NH) rl0 = ws_rlog[hr[b * NH + l]]; }

    float ssum = 0.f;
    float4 acc = make_float4(0.f, 0.f, 0.f, 0.f);

    // ---- history entries 0..47 (12 iters x 4 entries) ----
    #pragma unroll 4
    for (int k = 0; k < 12; ++k) {
        const float4 e = *(const float4*)(histTab + hidx[k] * ND + 4 * j);
        float part = e.x * ra4.x;
        part = fmaf(e.y, ra4.y, part);
        part = fmaf(e.z, ra4.z, part);
        part = fmaf(e.w, ra4.w, part);
        part += (j == k) ? rl0 : 0.f;
        part += __shfl_xor(part, 1);
        part += __shfl_xor(part, 2);
        part += __shfl_xor(part, 4);
        part += __shfl_xor(part, 8);
        const float p = __expf(part);
        ssum += p;
        acc.x = fmaf(p, e.x, acc.x);
        acc.y = fmaf(p, e.y, acc.y);
        acc.z = fmaf(p, e.z, acc.z);
        acc.w = fmaf(p, e.w, acc.w);
    }
    // ---- history tail: entries 48,49 on groups 0,1 ----
    {
        const float4 e = *(const float4*)(histTab + hidx[12] * ND + 4 * j);
        float part = e.x * ra4.x;
        part = fmaf(e.y, ra4.y, part);
        part = fmaf(e.z, ra4.z, part);
        part = fmaf(e.w, ra4.w, part);
        part += (j == 12) ? rl0 : 0.f;
        part += __shfl_xor(part, 1);
        part += __shfl_xor(part, 2);
        part += __shfl_xor(part, 4);
        part += __shfl_xor(part, 8);
        const float p = (g < 2) ? __expf(part) : 0.f;
        ssum += p;
        acc.x = fmaf(p, e.x, acc.x);
        acc.y = fmaf(p, e.y, acc.y);
        acc.z = fmaf(p, e.z, acc.z);
        acc.w = fmaf(p, e.w, acc.w);
    }
    // ---- adj entries 0..31 (8 iters x 4 entries), rate logit = rlog6 ----
    #pragma unroll 4
    for (int k = 0; k < 8; ++k) {
        const int idx = adj[b * NA + 4 * k + g];
        const float4 e = *(const float4*)(neighTab + idx * ND + 4 * j);
        float part = e.x * ra4.x;
        part = fmaf(e.y, ra4.y, part);
        part = fmaf(e.z, ra4.z, part);
        part = fmaf(e.w, ra4.w, part);
        part += __shfl_xor(part, 1);
        part += __shfl_xor(part, 2);
        part += __shfl_xor(part, 4);
        part += __shfl_xor(part, 8);
        const float p = __expf(part + rlog6);
        ssum += p;
        acc.x = fmaf(p, e.x, acc.x);
        acc.y = fmaf(p, e.y, acc.y);
        acc.z = fmaf(p, e.z, acc.z);
        acc.w = fmaf(p, e.w, acc.w);
    }

    // combine the 4 entry-groups (each group summed a disjoint entry subset)
    ssum += __shfl_xor(ssum, 16);
    ssum += __shfl_xor(ssum, 32);
    acc.x += __shfl_xor(acc.x, 16); acc.x += __shfl_xor(acc.x, 32);
    acc.y += __shfl_xor(acc.y, 16); acc.y += __shfl_xor(acc.y, 32);
    acc.z += __shfl_xor(acc.z, 16); acc.z += __shfl_xor(acc.z, 32);
    acc.w += __shfl_xor(acc.w, 16); acc.w += __shfl_xor(acc.w, 32);

    const float inv = 1.0f / ssum;
    const float4 nf4 = *(const float4*)(nodeTab + nodes[b] * ND + 4 * j);

    // comb -> own LDS slice (wave-local, wave-synchronous: no barrier)
    if (g == 0) {
        *(float4*)&lds_comb[wid][4 * j] = nf4;
        float4 n4 = make_float4(acc.x * inv, acc.y * inv, acc.z * inv, acc.w * inv);
        *(float4*)&lds_comb[wid][64 + 4 * j] = n4;
    }

    // out_j = relu(b_j + sum_k W[j][k] * comb[k]); lane = output j
    float o = lin1_b[lane];
    const float4* W4 = (const float4*)(lin1_W + lane * 128);
    const float4* C4 = (const float4*)lds_comb[wid];
    #pragma unroll 8
    for (int kk = 0; kk < 32; ++kk) {
        const float4 w = W4[kk];
        const float4 c = C4[kk];
        o = fmaf(w.x, c.x, o);
        o = fmaf(w.y, c.y, o);
        o = fmaf(w.z, c.z, o);
        o = fmaf(w.w, c.w, o);
    }
    const float evec = fmaxf(o, 0.f);

    ed[wid][lane] = evec;
    __syncthreads();

    if (wid < 2) {
        float prod = ed[wid][lane] * ed[wid + 2][lane];
        #pragma unroll
        for (int off = 32; off >= 1; off >>= 1)
            prod += __shfl_xor(prod, off);
        if (lane == 0) out[blockIdx.x * 2 + wid] = prod;
    }
}

extern "C" void kernel_launch(void* const* d_in, const int* in_sizes, int n_in,
                              void* d_out, int out_size, void* d_ws, size_t ws_size,
                              hipStream_t stream)
{
    const float* u2e     = (const float*)d_in[0];
    const float* v2e     = (const float*)d_in[1];
    const float* r2e     = (const float*)d_in[2];
    const float* ra      = (const float*)d_in[3];
    // d_in[4] agg_W, d_in[5] agg_b: dead code in the reference
    const float* lin1_W  = (const float*)d_in[6];
    const float* lin1_b  = (const float*)d_in[7];
    const int* nodes_u   = (const int*)d_in[8];
    const int* nodes_v   = (const int*)d_in[9];
    const int* hist_u    = (const int*)d_in[10];
    const int* hist_ur   = (const int*)d_in[11];
    const int* adj_u     = (const int*)d_in[12];
    const int* hist_v    = (const int*)d_in[13];
    const int* hist_vr   = (const int*)d_in[14];
    const int* adj_v     = (const int*)d_in[15];
    float* out = (float*)d_out;
    float* ws_rlog = (float*)d_ws;

    hipLaunchKernelGGL(rlog_setup, dim3(1), dim3(64), 0, stream, r2e, ra, ws_rlog);
    hipLaunchKernelGGL(graphconsis_main, dim3(NB / 2), dim3(256), 0, stream,
                       u2e, v2e, ra, lin1_W, lin1_b,
                       nodes_u, nodes_v, hist_u, hist_ur, adj_u,
                       hist_v, hist_vr, adj_v, ws_rlog, out);
}